// Round 1
// baseline (1822.642 us; speedup 1.0000x reference)
//
#include <hip/hip_runtime.h>

#define FDIM 75
#define CDIM 150          // 2*FDIM
#define NODE_STRIDE 80    // padded row stride (16B-aligned rows)
#define NPB 3             // nodes per block in update kernel

// ---- pad/copy input h [N,75] -> ws h [N,80] (pad cols zeroed) ----
__global__ void pad_copy_kernel(const float* __restrict__ h_in,
                                float* __restrict__ h_out, int n_nodes) {
    int idx = blockIdx.x * blockDim.x + threadIdx.x;
    int total = n_nodes * NODE_STRIDE;
    if (idx >= total) return;
    int v = idx / NODE_STRIDE;
    int f = idx - v * NODE_STRIDE;
    h_out[idx] = (f < FDIM) ? h_in[v * FDIM + f] : 0.0f;
}

// ---- message: m[dst] += h[src] over all edges (16 lanes per edge) ----
__global__ void scatter_kernel(const float* __restrict__ h,
                               float* __restrict__ m,
                               const int* __restrict__ esrc,
                               const int* __restrict__ edst, int n_edges) {
    int tid = threadIdx.x;
    int group = tid >> 4;
    int lane = tid & 15;
    int e = blockIdx.x * 16 + group;
    if (e >= n_edges) return;
    int src = esrc[e];
    int dst = edst[e];
    const float* hs = h + (size_t)src * NODE_STRIDE;
    float* md = m + (size_t)dst * NODE_STRIDE;
#pragma unroll
    for (int r = 0; r < 5; ++r) {
        int f = r * 16 + lane;
        if (f < FDIM) unsafeAtomicAdd(&md[f], hs[f]);
    }
}

// ---- update: h[v] = relu(U @ [h[v]; m[v]] + Ub), in place ----
__global__ __launch_bounds__(256) void update_kernel(
        float* __restrict__ h, const float* __restrict__ m,
        const float* __restrict__ Uw, const float* __restrict__ Ub,
        int n_nodes) {
    __shared__ float Ulds[FDIM * CDIM];       // 45000 B
    __shared__ float xlds[NPB][CDIM + 2];     // +2 pad
    int tid = threadIdx.x;
    for (int i = tid; i < FDIM * CDIM; i += 256) Ulds[i] = Uw[i];

    int v_local = tid / FDIM;                 // 0..2 active, 3 for tail threads
    int j = tid - v_local * FDIM;
    float bj = (v_local < NPB) ? Ub[j] : 0.0f;
    __syncthreads();

    for (int base = blockIdx.x * NPB; base < n_nodes; base += gridDim.x * NPB) {
        // stage [h[v]; m[v]] rows for NPB nodes into LDS
        for (int i = tid; i < NPB * (CDIM + 2); i += 256) {
            int nl = i / (CDIM + 2);
            int c = i - nl * (CDIM + 2);
            int v = base + nl;
            float val = 0.0f;
            if (v < n_nodes && c < CDIM) {
                val = (c < FDIM) ? h[(size_t)v * NODE_STRIDE + c]
                                 : m[(size_t)v * NODE_STRIDE + (c - FDIM)];
            }
            xlds[nl][c] = val;
        }
        __syncthreads();
        if (v_local < NPB) {
            int v = base + v_local;
            if (v < n_nodes) {
                float acc = bj;
                const float* urow = &Ulds[j * CDIM];
                const float* x = &xlds[v_local][0];
#pragma unroll 10
                for (int k = 0; k < CDIM; ++k) acc = fmaf(urow[k], x[k], acc);
                h[(size_t)v * NODE_STRIDE + j] = fmaxf(acc, 0.0f);
            }
        }
        __syncthreads();
    }
}

// ---- readout init: out[i] = NN_b ----
__global__ void readout_init_kernel(float* __restrict__ out,
                                    const float* __restrict__ NN_b,
                                    int num_mols) {
    int i = blockIdx.x * blockDim.x + threadIdx.x;
    if (i < num_mols) out[i] = NN_b[0];
}

// ---- readout: out[mol_id[v]] += dot(h[v], NN_w) (16 lanes per node) ----
__global__ void readout_kernel(const float* __restrict__ h,
                               const float* __restrict__ NNw,
                               const int* __restrict__ mol_id,
                               float* __restrict__ out, int n_nodes) {
    int tid = threadIdx.x;
    int group = tid >> 4;
    int lane = tid & 15;
    int v = blockIdx.x * 16 + group;
    if (v >= n_nodes) return;
    float acc = 0.0f;
#pragma unroll
    for (int r = 0; r < 5; ++r) {
        int f = r * 16 + lane;
        if (f < FDIM) acc += h[(size_t)v * NODE_STRIDE + f] * NNw[f];
    }
    acc += __shfl_down(acc, 8, 16);
    acc += __shfl_down(acc, 4, 16);
    acc += __shfl_down(acc, 2, 16);
    acc += __shfl_down(acc, 1, 16);
    if (lane == 0) unsafeAtomicAdd(&out[mol_id[v]], acc);
}

extern "C" void kernel_launch(void* const* d_in, const int* in_sizes, int n_in,
                              void* d_out, int out_size, void* d_ws, size_t ws_size,
                              hipStream_t stream) {
    const float* h_in  = (const float*)d_in[0];
    const float* U_w   = (const float*)d_in[1];
    const float* U_b   = (const float*)d_in[2];
    const float* NN_w  = (const float*)d_in[3];
    const float* NN_b  = (const float*)d_in[4];
    const int*   esrc  = (const int*)d_in[5];
    const int*   edst  = (const int*)d_in[6];
    const int*   molid = (const int*)d_in[7];

    int n_nodes  = in_sizes[0] / FDIM;   // 100000
    int n_edges  = in_sizes[5];          // 1600000
    int num_mols = out_size;             // 1024
    const int depth = 3;                 // reference DEPTH

    float* h = (float*)d_ws;
    float* m = h + (size_t)n_nodes * NODE_STRIDE;
    float* out = (float*)d_out;

    size_t row_bytes = (size_t)n_nodes * NODE_STRIDE * sizeof(float);

    pad_copy_kernel<<<(n_nodes * NODE_STRIDE + 255) / 256, 256, 0, stream>>>(
        h_in, h, n_nodes);

    for (int d = 0; d < depth; ++d) {
        hipMemsetAsync(m, 0, row_bytes, stream);
        scatter_kernel<<<(n_edges + 15) / 16, 256, 0, stream>>>(
            h, m, esrc, edst, n_edges);
        update_kernel<<<8192, 256, 0, stream>>>(h, m, U_w, U_b, n_nodes);
    }

    readout_init_kernel<<<(num_mols + 255) / 256, 256, 0, stream>>>(
        out, NN_b, num_mols);
    readout_kernel<<<(n_nodes + 15) / 16, 256, 0, stream>>>(
        h, NN_w, molid, out, n_nodes);
}